// Round 13
// baseline (1700.567 us; speedup 1.0000x reference)
//
#include <hip/hip_runtime.h>

#define L_SEQ 2048
#define C_IN  64
#define HH    128
#define NSEQ  32
#define G3    384
#define XW32  (C_IN / 2)                 // 32 u32 per packed x row
#define XTOT  (NSEQ * L_SEQ * XW32)

typedef _Float16 f16x8 __attribute__((ext_vector_type(8)));
typedef float    f32x4 __attribute__((ext_vector_type(4)));
typedef _Float16 half2_t __attribute__((ext_vector_type(2)));

// per-step barrier: drain LDS only; vmcnt (out stores, x prefetch) floats
#define STEP_BARRIER() asm volatile("s_waitcnt lgkmcnt(0)\n\ts_barrier" ::: "memory")
#define MFMA16(a, b, c) __builtin_amdgcn_mfma_f32_16x16x32_f16((a), (b), (c), 0, 0, 0)

__device__ __forceinline__ unsigned int pack_h2(float a, float b) {
    half2_t t; t.x = (_Float16)a; t.y = (_Float16)b;
    return __builtin_bit_cast(unsigned int, t);
}
__device__ __forceinline__ f16x8 ld_frag_g(const unsigned int* p) {
    return __builtin_bit_cast(f16x8, *(const uint4*)p);
}
__device__ __forceinline__ float fast_sigmoid(float x) {
    float e = __builtin_amdgcn_exp2f(-1.4426950408889634f * x);
    return __builtin_amdgcn_rcpf(1.0f + e);
}
__device__ __forceinline__ float fast_tanh(float x) {
    float a = fabsf(x);
    float e = __builtin_amdgcn_exp2f(-2.8853900817779268f * a);  // e^{-2a}
    float r = (1.0f - e) * __builtin_amdgcn_rcpf(1.0f + e);
    return copysignf(r, x);
}

// ---------------------------------------------------------------------------
// Pre-pass: pack x (f32) -> f16-pair rows in ws, plus one zero row at the end.
// ---------------------------------------------------------------------------
__global__ __launch_bounds__(256)
void pack_x_kernel(const float* __restrict__ x, unsigned int* __restrict__ xh)
{
    const size_t i = (size_t)blockIdx.x * 256 + threadIdx.x;
    if (i < (size_t)XTOT) {
        const float2 v = ((const float2*)x)[i];
        xh[i] = pack_h2(v.x, v.y);
    }
    if (i < XW32) xh[(size_t)XTOT + i] = 0u;     // zero row for ragged tail
}

// ---------------------------------------------------------------------------
// Fused MFMA BiGRU: 32 blocks x 512 threads = 8 waves = TWO sequences/block.
//   waves 0-3: seq s=blk (fwd);  waves 4-7: seq s=blk+32 (rev, same x in L2).
//   Each SIMD hosts one wave of EACH sequence -> two independent instruction
//   streams per SIMD hide each other's serial chain (r8's proven mechanism).
// Per wave per step (cols [32w,32w+32) of all gates):
//   r,z: fused K=192 [h(128)|x(64)] -> 6 K-tiles each.  n = tanh(xn + r*hn):
//   hn h-only (4 Kt), xn x-only (2 Kt).  36 MFMA total; A-frags broadcast
//   from the 256 B LDS h-row (all 16 M-rows equal) + packed-f16 x row.
// B-frags 36 x f16x8 = 144 regs; overflow->AGPR is fine (MFMA reads AGPR).
// Epilogue: 2 gate-triples/lane; lg==0 writes h (f16 LDS) + out (f32).
// One lgkm-only barrier per step. No xw buffer, no chunking, single launch.
// A: row=lane&15, k=(lane>>4)*8+i. B: col=lane&15, same k. C: [0] (rows eq).
// ---------------------------------------------------------------------------
__global__ __launch_bounds__(512) __attribute__((amdgpu_waves_per_eu(2, 2)))
void bigru_mfma2(const unsigned int* __restrict__ xh,
                 const int* __restrict__ lengths,
                 const float* __restrict__ W_ih, const float* __restrict__ W_hh,
                 const float* __restrict__ b_ih, const float* __restrict__ b_hh,
                 float* __restrict__ out)
{
    __shared__ _Float16 hrow[2][2][HH];   // [seq-role][buf][col], 1 KB total

    const int tid = threadIdx.x;
    const int q   = tid >> 8;             // role: 0 = fwd seq, 1 = rev seq
    const int u   = tid & 255;
    const int w   = u >> 6;               // wave-in-role -> cols [32w, 32w+32)
    const int l   = u & 63;
    const int lm  = l & 15;
    const int lg  = l >> 4;
    const int col0 = 32 * w + lm;
    const int col1 = col0 + 16;
    const bool fwd = (q == 0);

    // ---- persistent B fragments (fused rz over K=192; hn 4Kt; xn 2Kt) ----
    f16x8 Br[2][6], Bz[2][6], Bhn[2][4], Bxn[2][2];
#pragma unroll
    for (int e = 0; e < 2; ++e) {
        const int col = 32 * w + 16 * e + lm;
#pragma unroll
        for (int kt = 0; kt < 6; ++kt) {
            f16x8 fr, fz;
#pragma unroll
            for (int i = 0; i < 8; ++i) {
                const int k = kt * 32 + lg * 8 + i;          // fused K: h then x
                const float vr = (k < HH) ? W_hh[k * G3 + col]
                                          : W_ih[(k - HH) * G3 + col];
                const float vz = (k < HH) ? W_hh[k * G3 + 128 + col]
                                          : W_ih[(k - HH) * G3 + 128 + col];
                fr[i] = (_Float16)vr; fz[i] = (_Float16)vz;
            }
            Br[e][kt] = fr; Bz[e][kt] = fz;
        }
#pragma unroll
        for (int kt = 0; kt < 4; ++kt) {
            f16x8 f;
#pragma unroll
            for (int i = 0; i < 8; ++i)
                f[i] = (_Float16)W_hh[(kt * 32 + lg * 8 + i) * G3 + 256 + col];
            Bhn[e][kt] = f;
        }
#pragma unroll
        for (int kt = 0; kt < 2; ++kt) {
            f16x8 f;
#pragma unroll
            for (int i = 0; i < 8; ++i)
                f[i] = (_Float16)W_ih[(kt * 32 + lg * 8 + i) * G3 + 256 + col];
            Bxn[e][kt] = f;
        }
    }
    float biasR[2], biasZ[2], biasHN[2], biasXN[2];
#pragma unroll
    for (int e = 0; e < 2; ++e) {
        const int col = 32 * w + 16 * e + lm;
        biasR[e]  = b_ih[col] + b_hh[col];
        biasZ[e]  = b_ih[128 + col] + b_hh[128 + col];
        biasHN[e] = b_hh[256 + col];
        biasXN[e] = b_ih[256 + col];
    }

    // ---- x addressing (block-uniform per role) ----
    const int sb = blockIdx.x;            // batch element 0..31
    const unsigned int* __restrict__ xbase = xh + (size_t)sb * L_SEQ * XW32;
    const unsigned int* __restrict__ zrow  = xh + (size_t)XTOT;
    const int len = fwd ? L_SEQ : lengths[sb];

    auto xrow = [&](int t) -> const unsigned int* {
        const int src = fwd ? t : (len - 1 - t);
        return ((unsigned)src < (unsigned)L_SEQ) ? (xbase + (size_t)src * XW32)
                                                 : zrow;
    };

    float* outbase = out + (size_t)sb * L_SEQ * 256 + (fwd ? 0 : HH);

    // ---- init h ----
    float ho0 = 0.f, ho1 = 0.f;
    if (u < HH) hrow[q][0][u] = (_Float16)0.f;
    __syncthreads();

    // prefetch x frags for t = 0
    f16x8 Ax0, Ax1;
    { const unsigned int* p = xrow(0);
      Ax0 = ld_frag_g(p + lg * 4); Ax1 = ld_frag_g(p + 16 + lg * 4); }

    int cur = 0;
    for (int t = 0; t < L_SEQ; ++t) {
        // A h-fragments: broadcast reads of this role's h row
        const uint4* hb = (const uint4*)&hrow[q][cur][0];
        const f16x8 A0 = __builtin_bit_cast(f16x8, hb[0 * 4 + lg]);
        const f16x8 A1 = __builtin_bit_cast(f16x8, hb[1 * 4 + lg]);
        const f16x8 A2 = __builtin_bit_cast(f16x8, hb[2 * 4 + lg]);
        const f16x8 A3 = __builtin_bit_cast(f16x8, hb[3 * 4 + lg]);

        // prefetch next step's x frags (vmcnt floats across the barrier)
        f16x8 AxN0, AxN1;
        { const unsigned int* p = xrow(t + 1);
          AxN0 = ld_frag_g(p + lg * 4); AxN1 = ld_frag_g(p + 16 + lg * 4); }

        // ---- 36 MFMA: 6 accumulators ----
        f32x4 cr0 = {biasR[0], biasR[0], biasR[0], biasR[0]};
        f32x4 cz0 = {biasZ[0], biasZ[0], biasZ[0], biasZ[0]};
        f32x4 hn0 = {biasHN[0], biasHN[0], biasHN[0], biasHN[0]};
        f32x4 xn0 = {biasXN[0], biasXN[0], biasXN[0], biasXN[0]};
        f32x4 cr1 = {biasR[1], biasR[1], biasR[1], biasR[1]};
        f32x4 cz1 = {biasZ[1], biasZ[1], biasZ[1], biasZ[1]};
        f32x4 hn1 = {biasHN[1], biasHN[1], biasHN[1], biasHN[1]};
        f32x4 xn1 = {biasXN[1], biasXN[1], biasXN[1], biasXN[1]};

        cr0 = MFMA16(A0, Br[0][0], cr0); cr0 = MFMA16(A1, Br[0][1], cr0);
        cr0 = MFMA16(A2, Br[0][2], cr0); cr0 = MFMA16(A3, Br[0][3], cr0);
        cr0 = MFMA16(Ax0, Br[0][4], cr0); cr0 = MFMA16(Ax1, Br[0][5], cr0);
        cz0 = MFMA16(A0, Bz[0][0], cz0); cz0 = MFMA16(A1, Bz[0][1], cz0);
        cz0 = MFMA16(A2, Bz[0][2], cz0); cz0 = MFMA16(A3, Bz[0][3], cz0);
        cz0 = MFMA16(Ax0, Bz[0][4], cz0); cz0 = MFMA16(Ax1, Bz[0][5], cz0);
        hn0 = MFMA16(A0, Bhn[0][0], hn0); hn0 = MFMA16(A1, Bhn[0][1], hn0);
        hn0 = MFMA16(A2, Bhn[0][2], hn0); hn0 = MFMA16(A3, Bhn[0][3], hn0);
        xn0 = MFMA16(Ax0, Bxn[0][0], xn0); xn0 = MFMA16(Ax1, Bxn[0][1], xn0);

        cr1 = MFMA16(A0, Br[1][0], cr1); cr1 = MFMA16(A1, Br[1][1], cr1);
        cr1 = MFMA16(A2, Br[1][2], cr1); cr1 = MFMA16(A3, Br[1][3], cr1);
        cr1 = MFMA16(Ax0, Br[1][4], cr1); cr1 = MFMA16(Ax1, Br[1][5], cr1);
        cz1 = MFMA16(A0, Bz[1][0], cz1); cz1 = MFMA16(A1, Bz[1][1], cz1);
        cz1 = MFMA16(A2, Bz[1][2], cz1); cz1 = MFMA16(A3, Bz[1][3], cz1);
        cz1 = MFMA16(Ax0, Bz[1][4], cz1); cz1 = MFMA16(Ax1, Bz[1][5], cz1);
        hn1 = MFMA16(A0, Bhn[1][0], hn1); hn1 = MFMA16(A1, Bhn[1][1], hn1);
        hn1 = MFMA16(A2, Bhn[1][2], hn1); hn1 = MFMA16(A3, Bhn[1][3], hn1);
        xn1 = MFMA16(Ax0, Bxn[1][0], xn1); xn1 = MFMA16(Ax1, Bxn[1][1], xn1);

        // ---- gates (all C rows equal -> [0]) ----
        const float r0 = fast_sigmoid(cr0[0]);
        const float z0 = fast_sigmoid(cz0[0]);
        const float n0 = fast_tanh(xn0[0] + r0 * hn0[0]);
        const float h0 = z0 * (ho0 - n0) + n0;
        ho0 = h0;
        const float r1 = fast_sigmoid(cr1[0]);
        const float z1 = fast_sigmoid(cz1[0]);
        const float n1 = fast_tanh(xn1[0] + r1 * hn1[0]);
        const float h1 = z1 * (ho1 - n1) + n1;
        ho1 = h1;

        if (lg == 0) {
            hrow[q][cur ^ 1][col0] = (_Float16)h0;
            hrow[q][cur ^ 1][col1] = (_Float16)h1;
            float* op = outbase + (size_t)t * 256;
            op[col0] = h0;
            op[col1] = h1;
        }
        STEP_BARRIER();
        cur ^= 1;
        Ax0 = AxN0; Ax1 = AxN1;
    }
}

// ---------------------------------------------------------------------------
extern "C" void kernel_launch(void* const* d_in, const int* in_sizes, int n_in,
                              void* d_out, int out_size, void* d_ws, size_t ws_size,
                              hipStream_t stream) {
    const float* x       = (const float*)d_in[0];
    const int*   lengths = (const int*)  d_in[1];
    const float* W_ih    = (const float*)d_in[2];
    const float* W_hh    = (const float*)d_in[3];
    const float* b_ih    = (const float*)d_in[4];
    const float* b_hh    = (const float*)d_in[5];
    float* out = (float*)d_out;

    unsigned int* xh = (unsigned int*)d_ws;      // (XTOT + XW32) u32 = 8.4 MB

    pack_x_kernel<<<dim3((XTOT + 255) / 256), dim3(256), 0, stream>>>(x, xh);
    bigru_mfma2<<<dim3(NSEQ), dim3(512), 0, stream>>>(
        xh, lengths, W_ih, W_hh, b_ih, b_hh, out);
}

// Round 14
// 1036.852 us; speedup vs baseline: 1.6401x; 1.6401x over previous
//
#include <hip/hip_runtime.h>

#define L_SEQ 2048
#define C_IN  64
#define HH    128
#define NSEQ  32
#define B2    64
#define G3    384
#define XW32  (C_IN / 2)                 // 32 u32 per packed x row
#define XTOT  (NSEQ * L_SEQ * XW32)

typedef _Float16 f16x8 __attribute__((ext_vector_type(8)));
typedef float    f32x4 __attribute__((ext_vector_type(4)));
typedef _Float16 half2_t __attribute__((ext_vector_type(2)));

// per-step barrier: drain LDS only; vmcnt (out stores, x prefetch) floats
#define STEP_BARRIER() asm volatile("s_waitcnt lgkmcnt(0)\n\ts_barrier" ::: "memory")
#define MFMA16(a, b, c) __builtin_amdgcn_mfma_f32_16x16x32_f16((a), (b), (c), 0, 0, 0)

__device__ __forceinline__ unsigned int pack_h2(float a, float b) {
    half2_t t; t.x = (_Float16)a; t.y = (_Float16)b;
    return __builtin_bit_cast(unsigned int, t);
}
__device__ __forceinline__ f16x8 ld_frag_g(const unsigned int* p) {
    return __builtin_bit_cast(f16x8, *(const uint4*)p);
}
__device__ __forceinline__ float fast_sigmoid(float x) {
    float e = __builtin_amdgcn_exp2f(-1.4426950408889634f * x);
    return __builtin_amdgcn_rcpf(1.0f + e);
}
__device__ __forceinline__ float fast_tanh(float x) {
    float a = fabsf(x);
    float e = __builtin_amdgcn_exp2f(-2.8853900817779268f * a);  // e^{-2a}
    float r = (1.0f - e) * __builtin_amdgcn_rcpf(1.0f + e);
    return copysignf(r, x);
}

// ---------------------------------------------------------------------------
// Pre-pass: pack x (f32) -> f16-pair rows in ws, plus one zero row at the end.
// ---------------------------------------------------------------------------
__global__ __launch_bounds__(256)
void pack_x_kernel(const float* __restrict__ x, unsigned int* __restrict__ xh)
{
    const size_t i = (size_t)blockIdx.x * 256 + threadIdx.x;
    if (i < (size_t)XTOT) {
        const float2 v = ((const float2*)x)[i];
        xh[i] = pack_h2(v.x, v.y);
    }
    if (i < XW32) xh[(size_t)XTOT + i] = 0u;     // zero row for ragged tail
}

// ---------------------------------------------------------------------------
// Fused MFMA BiGRU: 64 blocks x 256 threads (4 waves), ONE sequence/block.
// The proven spill-free shape (256 thr + waves_per_eu(1,1); r7/r12: VGPR
// stays resident). Wave w owns gate columns [32w, 32w+32).
// Per step, per wave: 36 MFMA —
//   r,z: fused K=192 over [h(128) | x(64)] -> 6 K-tiles each;
//   hn: h-only 4 K-tiles;  xn: x-only 2 K-tiles  (n = tanh(xn + r*hn)).
// The 12 x-MFMAs are independent of h -> they issue inside the h-chain's
// ds_read/MFMA latency shadow (ILP replaces the failed cross-wave TLP).
// x comes as A-frags from the 8.4 MB packed-f16 buffer (L3-resident), so
// there is NO xw kernel, no 400 MB of xw HBM traffic, no deep-latency
// global gather per step. A-frag h: broadcast from 256 B LDS row (all 16
// M-rows equal -> C reg [0] is the value; layouts r11/r12-validated).
// Epilogue: 2 gate-triples/lane; lg==0 writes h (f16 LDS) + out (f32,
// lanes 0..15 -> 64 B coalesced). One lgkm-only barrier per step.
// ---------------------------------------------------------------------------
__global__ __launch_bounds__(256) __attribute__((amdgpu_waves_per_eu(1, 1)))
void bigru_mfma(const unsigned int* __restrict__ xh,
                const int* __restrict__ lengths,
                const float* __restrict__ W_ih, const float* __restrict__ W_hh,
                const float* __restrict__ b_ih, const float* __restrict__ b_hh,
                float* __restrict__ out)
{
    __shared__ _Float16 hrow[2][HH];      // 256 B per buffer, double-buffered

    const int tid = threadIdx.x;
    const int w   = tid >> 6;             // wave 0..3 -> cols [32w, 32w+32)
    const int l   = tid & 63;
    const int lm  = l & 15;
    const int lg  = l >> 4;
    const int col0 = 32 * w + lm;
    const int col1 = col0 + 16;
    const int s   = blockIdx.x;
    const bool fwd = (s < NSEQ);

    // ---- persistent B fragments (rz fused K=192; hn 4 Kt; xn 2 Kt) ----
    f16x8 Br[2][6], Bz[2][6], Bhn[2][4], Bxn[2][2];
#pragma unroll
    for (int e = 0; e < 2; ++e) {
        const int col = 32 * w + 16 * e + lm;
#pragma unroll
        for (int kt = 0; kt < 6; ++kt) {
            f16x8 fr, fz;
#pragma unroll
            for (int i = 0; i < 8; ++i) {
                const int k = kt * 32 + lg * 8 + i;          // fused K: h then x
                const float vr = (k < HH) ? W_hh[k * G3 + col]
                                          : W_ih[(k - HH) * G3 + col];
                const float vz = (k < HH) ? W_hh[k * G3 + 128 + col]
                                          : W_ih[(k - HH) * G3 + 128 + col];
                fr[i] = (_Float16)vr; fz[i] = (_Float16)vz;
            }
            Br[e][kt] = fr; Bz[e][kt] = fz;
        }
#pragma unroll
        for (int kt = 0; kt < 4; ++kt) {
            f16x8 f;
#pragma unroll
            for (int i = 0; i < 8; ++i)
                f[i] = (_Float16)W_hh[(kt * 32 + lg * 8 + i) * G3 + 256 + col];
            Bhn[e][kt] = f;
        }
#pragma unroll
        for (int kt = 0; kt < 2; ++kt) {
            f16x8 f;
#pragma unroll
            for (int i = 0; i < 8; ++i)
                f[i] = (_Float16)W_ih[(kt * 32 + lg * 8 + i) * G3 + 256 + col];
            Bxn[e][kt] = f;
        }
    }
    float biasR[2], biasZ[2], biasHN[2], biasXN[2];
#pragma unroll
    for (int e = 0; e < 2; ++e) {
        const int col = 32 * w + 16 * e + lm;
        biasR[e]  = b_ih[col] + b_hh[col];
        biasZ[e]  = b_ih[128 + col] + b_hh[128 + col];
        biasHN[e] = b_hh[256 + col];
        biasXN[e] = b_ih[256 + col];
    }

    // ---- x addressing (block-uniform) ----
    const unsigned int* __restrict__ xbase = xh + (size_t)(s % NSEQ) * L_SEQ * XW32;
    const unsigned int* __restrict__ zrow  = xh + (size_t)XTOT;
    const int len = fwd ? L_SEQ : lengths[s - NSEQ];

    auto xrow = [&](int t) -> const unsigned int* {
        const int src = fwd ? t : (len - 1 - t);
        return ((unsigned)src < (unsigned)L_SEQ) ? (xbase + (size_t)src * XW32)
                                                 : zrow;
    };

    float* outbase = out + (size_t)(s % NSEQ) * L_SEQ * 256 + (fwd ? 0 : HH);

    // ---- init h ----
    float ho0 = 0.f, ho1 = 0.f;
    if (tid < HH) hrow[0][tid] = (_Float16)0.f;
    __syncthreads();

    // prefetch x frags for t = 0
    f16x8 Ax0, Ax1;
    { const unsigned int* p = xrow(0);
      Ax0 = ld_frag_g(p + lg * 4); Ax1 = ld_frag_g(p + 16 + lg * 4); }

    int cur = 0;
    for (int t = 0; t < L_SEQ; ++t) {
        // A h-fragments: broadcast reads of the h row
        const uint4* hb = (const uint4*)&hrow[cur][0];
        const f16x8 A0 = __builtin_bit_cast(f16x8, hb[0 * 4 + lg]);
        const f16x8 A1 = __builtin_bit_cast(f16x8, hb[1 * 4 + lg]);
        const f16x8 A2 = __builtin_bit_cast(f16x8, hb[2 * 4 + lg]);
        const f16x8 A3 = __builtin_bit_cast(f16x8, hb[3 * 4 + lg]);

        // prefetch next step's x frags (L3-resident; vmcnt floats)
        f16x8 AxN0, AxN1;
        { const unsigned int* p = xrow(t + 1);
          AxN0 = ld_frag_g(p + lg * 4); AxN1 = ld_frag_g(p + 16 + lg * 4); }

        // ---- 36 MFMA: x-MFMAs first (independent -> fill h-latency shadow)
        f32x4 cr0 = {biasR[0], biasR[0], biasR[0], biasR[0]};
        f32x4 cz0 = {biasZ[0], biasZ[0], biasZ[0], biasZ[0]};
        f32x4 hn0 = {biasHN[0], biasHN[0], biasHN[0], biasHN[0]};
        f32x4 xn0 = {biasXN[0], biasXN[0], biasXN[0], biasXN[0]};
        f32x4 cr1 = {biasR[1], biasR[1], biasR[1], biasR[1]};
        f32x4 cz1 = {biasZ[1], biasZ[1], biasZ[1], biasZ[1]};
        f32x4 hn1 = {biasHN[1], biasHN[1], biasHN[1], biasHN[1]};
        f32x4 xn1 = {biasXN[1], biasXN[1], biasXN[1], biasXN[1]};

        cr0 = MFMA16(Ax0, Br[0][4], cr0); cr0 = MFMA16(Ax1, Br[0][5], cr0);
        cz0 = MFMA16(Ax0, Bz[0][4], cz0); cz0 = MFMA16(Ax1, Bz[0][5], cz0);
        xn0 = MFMA16(Ax0, Bxn[0][0], xn0); xn0 = MFMA16(Ax1, Bxn[0][1], xn0);
        cr1 = MFMA16(Ax0, Br[1][4], cr1); cr1 = MFMA16(Ax1, Br[1][5], cr1);
        cz1 = MFMA16(Ax0, Bz[1][4], cz1); cz1 = MFMA16(Ax1, Bz[1][5], cz1);
        xn1 = MFMA16(Ax0, Bxn[1][0], xn1); xn1 = MFMA16(Ax1, Bxn[1][1], xn1);

        cr0 = MFMA16(A0, Br[0][0], cr0); cr0 = MFMA16(A1, Br[0][1], cr0);
        cr0 = MFMA16(A2, Br[0][2], cr0); cr0 = MFMA16(A3, Br[0][3], cr0);
        cz0 = MFMA16(A0, Bz[0][0], cz0); cz0 = MFMA16(A1, Bz[0][1], cz0);
        cz0 = MFMA16(A2, Bz[0][2], cz0); cz0 = MFMA16(A3, Bz[0][3], cz0);
        hn0 = MFMA16(A0, Bhn[0][0], hn0); hn0 = MFMA16(A1, Bhn[0][1], hn0);
        hn0 = MFMA16(A2, Bhn[0][2], hn0); hn0 = MFMA16(A3, Bhn[0][3], hn0);
        cr1 = MFMA16(A0, Br[1][0], cr1); cr1 = MFMA16(A1, Br[1][1], cr1);
        cr1 = MFMA16(A2, Br[1][2], cr1); cr1 = MFMA16(A3, Br[1][3], cr1);
        cz1 = MFMA16(A0, Bz[1][0], cz1); cz1 = MFMA16(A1, Bz[1][1], cz1);
        cz1 = MFMA16(A2, Bz[1][2], cz1); cz1 = MFMA16(A3, Bz[1][3], cz1);
        hn1 = MFMA16(A0, Bhn[1][0], hn1); hn1 = MFMA16(A1, Bhn[1][1], hn1);
        hn1 = MFMA16(A2, Bhn[1][2], hn1); hn1 = MFMA16(A3, Bhn[1][3], hn1);

        // ---- gates (all C rows equal -> [0]) ----
        const float r0 = fast_sigmoid(cr0[0]);
        const float z0 = fast_sigmoid(cz0[0]);
        const float n0 = fast_tanh(xn0[0] + r0 * hn0[0]);
        const float h0 = z0 * (ho0 - n0) + n0;
        ho0 = h0;
        const float r1 = fast_sigmoid(cr1[0]);
        const float z1 = fast_sigmoid(cz1[0]);
        const float n1 = fast_tanh(xn1[0] + r1 * hn1[0]);
        const float h1 = z1 * (ho1 - n1) + n1;
        ho1 = h1;

        if (lg == 0) {
            hrow[cur ^ 1][col0] = (_Float16)h0;
            hrow[cur ^ 1][col1] = (_Float16)h1;
            float* op = outbase + (size_t)t * 256;
            op[col0] = h0;
            op[col1] = h1;
        }
        STEP_BARRIER();
        cur ^= 1;
        Ax0 = AxN0; Ax1 = AxN1;
    }
}

// ---------------------------------------------------------------------------
extern "C" void kernel_launch(void* const* d_in, const int* in_sizes, int n_in,
                              void* d_out, int out_size, void* d_ws, size_t ws_size,
                              hipStream_t stream) {
    const float* x       = (const float*)d_in[0];
    const int*   lengths = (const int*)  d_in[1];
    const float* W_ih    = (const float*)d_in[2];
    const float* W_hh    = (const float*)d_in[3];
    const float* b_ih    = (const float*)d_in[4];
    const float* b_hh    = (const float*)d_in[5];
    float* out = (float*)d_out;

    unsigned int* xh = (unsigned int*)d_ws;      // (XTOT + XW32) u32 = 8.4 MB

    pack_x_kernel<<<dim3((XTOT + 255) / 256), dim3(256), 0, stream>>>(x, xh);
    bigru_mfma<<<dim3(B2), dim3(256), 0, stream>>>(
        xh, lengths, W_ih, W_hh, b_ih, b_hh, out);
}

// Round 15
// 943.489 us; speedup vs baseline: 1.8024x; 1.0990x over previous
//
#include <hip/hip_runtime.h>

#define L_SEQ 2048
#define C_IN  64
#define HH    128
#define NSEQ  32
#define B2    64
#define G3    384
#define XW32  (C_IN / 2)                 // 32 u32 per packed x row
#define XTOT  (NSEQ * L_SEQ * XW32)
#define RSLOT 48                         // ring: 3 windows x 16 steps
#define RG    130                        // ring col stride (128 + 2 pad)

typedef _Float16 f16x8 __attribute__((ext_vector_type(8)));
typedef float    f32x4 __attribute__((ext_vector_type(4)));
typedef _Float16 half2_t __attribute__((ext_vector_type(2)));

#define PINU(v) asm volatile("" : "+v"(v))
// per-step barrier: drain LDS only; vmcnt (out stores, x loads) floats
#define STEP_BARRIER() asm volatile("s_waitcnt lgkmcnt(0)\n\ts_barrier" ::: "memory")
#define MFMA16(a, b, c) __builtin_amdgcn_mfma_f32_16x16x32_f16((a), (b), (c), 0, 0, 0)

__device__ __forceinline__ float fdot2u(unsigned int a, unsigned int b, float c) {
    return __builtin_amdgcn_fdot2(__builtin_bit_cast(half2_t, a),
                                  __builtin_bit_cast(half2_t, b), c, false);
}
__device__ __forceinline__ unsigned int pack_h2(float a, float b) {
    half2_t t; t.x = (_Float16)a; t.y = (_Float16)b;
    return __builtin_bit_cast(unsigned int, t);
}
// quad-perm DPP add: reduce across lane^1, pure VALU (no DS pipe)
__device__ __forceinline__ float qadd1(float x) {
    int t = __builtin_amdgcn_update_dpp(0, __builtin_bit_cast(int, x),
                                        0xB1, 0xF, 0xF, true); // [1,0,3,2]
    return x + __builtin_bit_cast(float, t);
}
__device__ __forceinline__ float fast_sigmoid(float x) {
    float e = __builtin_amdgcn_exp2f(-1.4426950408889634f * x);
    return __builtin_amdgcn_rcpf(1.0f + e);
}
__device__ __forceinline__ float fast_tanh(float x) {
    float a = fabsf(x);
    float e = __builtin_amdgcn_exp2f(-2.8853900817779268f * a);  // e^{-2a}
    float r = (1.0f - e) * __builtin_amdgcn_rcpf(1.0f + e);
    return copysignf(r, x);
}

// ---------------------------------------------------------------------------
// Pre-pass: pack x (f32) -> f16-pair rows in ws, plus one zero row at the end.
// ---------------------------------------------------------------------------
__global__ __launch_bounds__(256)
void pack_x_kernel(const float* __restrict__ x, unsigned int* __restrict__ xh)
{
    const size_t i = (size_t)blockIdx.x * 256 + threadIdx.x;
    if (i < (size_t)XTOT) {
        const float2 v = ((const float2*)x)[i];
        xh[i] = pack_h2(v.x, v.y);
    }
    if (i < XW32) xh[(size_t)XTOT + i] = 0u;     // zero row for ragged tail
}

// ---------------------------------------------------------------------------
// Fused BiGRU: 64 blocks x 256 threads (4 waves), ONE sequence per block.
// RECURRENCE (VALU pipe, r7's proven core): thread = (col j = tid>>1,
//   K-half p = tid&1); 96 packed f16-pair W_hh u32 pinned in VGPRs;
//   96 v_dot2 per step (2 accumulators per gate to halve the dep chain);
//   one DPP qadd1 per gate; h f16 double-buffered in 512 B LDS.
// X-PROJECTION (matrix pipe): time-batched M=16 MFMA — every 16 steps each
//   wave computes xw for 16 future timesteps (its 96 gate-cols) with 12
//   mfma_f32_16x16x32_f16 (A rows = timesteps: NO M-waste) into a 48-slot
//   LDS ring (3 windows; writes [t+24,t+40) never alias live reads [t,t+24)).
//   x A-frags are per-lane rows from the packed-f16 buffer, loaded one
//   window (16 steps) ahead. The MFMAs run on the matrix pipe while the
//   same wave's dot2s occupy the VALU -> dual-pipe overlap, ~0.75 MFMA/step.
// One lgkm-only barrier per step; out-stores and x loads float on vmcnt.
// ---------------------------------------------------------------------------
__global__ __launch_bounds__(256) __attribute__((amdgpu_waves_per_eu(1, 1)))
void bigru_fused(const unsigned int* __restrict__ xh,
                 const int* __restrict__ lengths,
                 const float* __restrict__ W_ih, const float* __restrict__ W_hh,
                 const float* __restrict__ b_ih, const float* __restrict__ b_hh,
                 float* __restrict__ out)
{
    __shared__ unsigned int hbufu[2][64];        // h as f16 pairs, dbuf
    __shared__ float ring[RSLOT][3][RG];         // xw ring, ~74.9 KB

    const int tid = threadIdx.x;
    const int s   = blockIdx.x;
    const bool fwd = (s < NSEQ);
    const int  len = fwd ? L_SEQ : lengths[s - NSEQ];
    const unsigned int* __restrict__ xbase = xh + (size_t)(s % NSEQ) * L_SEQ * XW32;
    const unsigned int* __restrict__ zrow  = xh + (size_t)XTOT;

    // consumer (recurrence) identity
    const int j = tid >> 1;          // col 0..127
    const int p = tid & 1;           // K half
    // producer (MFMA) identity
    const int w  = tid >> 6;         // wave 0..3 -> gate cols [32w, 32w+32)
    const int l  = tid & 63;
    const int lm = l & 15;
    const int lg = l >> 4;

    // ---- recurrence weights: 96 packed f16-pair u32, pinned ----
    unsigned int wr[32], wz[32], wn[32];
    {
        const float* Wb = W_hh + (size_t)(64 * p) * G3;
#pragma unroll
        for (int k = 0; k < 32; ++k) {
            wr[k] = pack_h2(Wb[(2*k) * G3 + j],       Wb[(2*k+1) * G3 + j]);
            wz[k] = pack_h2(Wb[(2*k) * G3 + 128 + j], Wb[(2*k+1) * G3 + 128 + j]);
            wn[k] = pack_h2(Wb[(2*k) * G3 + 256 + j], Wb[(2*k+1) * G3 + 256 + j]);
        }
#pragma unroll
        for (int k = 0; k < 32; ++k) { PINU(wr[k]); PINU(wz[k]); PINU(wn[k]); }
    }
    float bn = b_hh[256 + j];
    PINU(bn);

    // ---- producer B-frags (W_ih) + folded biases ----
    f16x8 Bx[3][2][2];               // [gate][e-tile][kt]
    float pbias[3][2];
#pragma unroll
    for (int g = 0; g < 3; ++g)
#pragma unroll
        for (int e = 0; e < 2; ++e) {
            const int gc = g * 128 + 32 * w + 16 * e + lm;
            pbias[g][e] = b_ih[gc] + ((g < 2) ? b_hh[gc] : 0.f);
#pragma unroll
            for (int kt = 0; kt < 2; ++kt) {
                f16x8 f;
#pragma unroll
                for (int i = 0; i < 8; ++i)
                    f[i] = (_Float16)W_ih[(kt * 32 + lg * 8 + i) * G3 + gc];
                Bx[g][e][kt] = f;
            }
        }

    // ---- producer helpers ----
    uint4 AxP0, AxP1;                // x A-frags for the NEXT window
    auto loadA = [&](int rowBase) {
        const int row = rowBase + lm;
        const int src = fwd ? row : (len - 1 - row);
        const unsigned int* ptr = ((unsigned)src < (unsigned)L_SEQ)
                                ? (xbase + (size_t)src * XW32) : zrow;
        AxP0 = *(const uint4*)(ptr + lg * 4);
        AxP1 = *(const uint4*)(ptr + 16 + lg * 4);
    };
    auto produce = [&](int s0) {     // writes slots [s0, s0+16)
        const f16x8 A0 = __builtin_bit_cast(f16x8, AxP0);
        const f16x8 A1 = __builtin_bit_cast(f16x8, AxP1);
#pragma unroll
        for (int g = 0; g < 3; ++g)
#pragma unroll
            for (int e = 0; e < 2; ++e) {
                f32x4 acc = {pbias[g][e], pbias[g][e], pbias[g][e], pbias[g][e]};
                acc = MFMA16(A0, Bx[g][e][0], acc);
                acc = MFMA16(A1, Bx[g][e][1], acc);
                const int colw = 32 * w + 16 * e + lm;
#pragma unroll
                for (int q = 0; q < 4; ++q)
                    ring[s0 + lg * 4 + q][g][colw] = acc[q];
            }
    };

    // ---- h init ----
    float hreg = 0.f;
    if (tid < 64) hbufu[0][tid] = 0u;

    // ---- prologue: windows 0,1 produced; window 2 loads in flight ----
    loadA(0);  produce(0);
    loadA(16); produce(16);
    loadA(32);
    __syncthreads();

    float cr = ring[0][0][j], cz = ring[0][1][j], cn = ring[0][2][j];

    float* outbase = out + (size_t)(s % NSEQ) * L_SEQ * 256 + (fwd ? 0 : HH);
    int cur = 0;
    int slotN = 1;                   // ring slot of step t+1
    int s0 = 32;                     // slot base of next production

    for (int t = 0; t < L_SEQ; ++t) {
        // mid-window: produce rows [t+24, t+40) on the MATRIX pipe, then
        // issue next window's x loads (16 steps of latency cover)
        if ((t & 15) == 8) {
            if (t + 24 < L_SEQ) produce(s0);
            s0 += 16; if (s0 >= RSLOT) s0 -= RSLOT;
            if (t + 40 < L_SEQ) loadA(t + 40);
        }

        // prefetch next step's xw from the ring (LDS, short latency)
        const float nr = ring[slotN][0][j];
        const float nz = ring[slotN][1][j];
        const float nn = ring[slotN][2][j];
        ++slotN; if (slotN == RSLOT) slotN = 0;

        // 96 dot2 on the VALU pipe; 2 accumulators/gate halve the dep chain
        float arA = 0.f, azA = 0.f, anA = 0.f;
        float arB = 0.f, azB = 0.f, anB = 0.f;
        const uint4* hb = (const uint4*)&hbufu[cur][p * 32];
#pragma unroll
        for (int i = 0; i < 4; ++i) {
            const uint4 hv = hb[i];
            arA = fdot2u(hv.x, wr[4*i+0], arA); arA = fdot2u(hv.y, wr[4*i+1], arA);
            arA = fdot2u(hv.z, wr[4*i+2], arA); arA = fdot2u(hv.w, wr[4*i+3], arA);
            azA = fdot2u(hv.x, wz[4*i+0], azA); azA = fdot2u(hv.y, wz[4*i+1], azA);
            azA = fdot2u(hv.z, wz[4*i+2], azA); azA = fdot2u(hv.w, wz[4*i+3], azA);
            anA = fdot2u(hv.x, wn[4*i+0], anA); anA = fdot2u(hv.y, wn[4*i+1], anA);
            anA = fdot2u(hv.z, wn[4*i+2], anA); anA = fdot2u(hv.w, wn[4*i+3], anA);
        }
#pragma unroll
        for (int i = 4; i < 8; ++i) {
            const uint4 hv = hb[i];
            arB = fdot2u(hv.x, wr[4*i+0], arB); arB = fdot2u(hv.y, wr[4*i+1], arB);
            arB = fdot2u(hv.z, wr[4*i+2], arB); arB = fdot2u(hv.w, wr[4*i+3], arB);
            azB = fdot2u(hv.x, wz[4*i+0], azB); azB = fdot2u(hv.y, wz[4*i+1], azB);
            azB = fdot2u(hv.z, wz[4*i+2], azB); azB = fdot2u(hv.w, wz[4*i+3], azB);
            anB = fdot2u(hv.x, wn[4*i+0], anB); anB = fdot2u(hv.y, wn[4*i+1], anB);
            anB = fdot2u(hv.z, wn[4*i+2], anB); anB = fdot2u(hv.w, wn[4*i+3], anB);
        }
        float ar = arA + arB, az = azA + azB, an = anA + anB;
        ar = qadd1(ar); az = qadd1(az); an = qadd1(an);

        const float r = fast_sigmoid(cr + ar);
        const float z = fast_sigmoid(cz + az);
        const float n = fast_tanh(cn + r * (an + bn));
        const float hnew = z * (hreg - n) + n;
        hreg = hnew;

        if (p == 0) {
            ((_Float16*)&hbufu[cur ^ 1][0])[j] = (_Float16)hnew;
            outbase[(size_t)t * 256 + j] = hnew;
        }
        STEP_BARRIER();
        cur ^= 1;
        cr = nr; cz = nz; cn = nn;
    }
}

// ---------------------------------------------------------------------------
extern "C" void kernel_launch(void* const* d_in, const int* in_sizes, int n_in,
                              void* d_out, int out_size, void* d_ws, size_t ws_size,
                              hipStream_t stream) {
    const float* x       = (const float*)d_in[0];
    const int*   lengths = (const int*)  d_in[1];
    const float* W_ih    = (const float*)d_in[2];
    const float* W_hh    = (const float*)d_in[3];
    const float* b_ih    = (const float*)d_in[4];
    const float* b_hh    = (const float*)d_in[5];
    float* out = (float*)d_out;

    unsigned int* xh = (unsigned int*)d_ws;      // (XTOT + XW32) u32 = 8.4 MB

    pack_x_kernel<<<dim3((XTOT + 255) / 256), dim3(256), 0, stream>>>(x, xh);
    bigru_fused<<<dim3(B2), dim3(256), 0, stream>>>(
        xh, lengths, W_ih, W_hh, b_ih, b_hh, out);
}